// Round 2
// baseline (458.515 us; speedup 1.0000x reference)
//
#include <hip/hip_runtime.h>
#include <stdint.h>

#define HW 16384
#define Bn 16
#define Ln 24
#define Dn 256
#define Qn 256
#define Cn 256

typedef __attribute__((ext_vector_type(8))) short short8;
typedef __attribute__((ext_vector_type(4))) float f32x4;

__device__ __forceinline__ unsigned short f2bf(float f) {
  unsigned u = __builtin_bit_cast(unsigned, f);
  u += 0x7FFFu + ((u >> 16) & 1u);
  return (unsigned short)(u >> 16);
}
__device__ __forceinline__ float bf2f(unsigned short s) {
  return __builtin_bit_cast(float, (unsigned)s << 16);
}

__device__ __forceinline__ void gl_lds16(const void* gsrc, void* lds) {
  __builtin_amdgcn_global_load_lds(
      (const __attribute__((address_space(1))) unsigned int*)gsrc,
      (__attribute__((address_space(3))) unsigned int*)lds, 16, 0, 0);
}

// ---------------- kernel 1: k[b,l,q] = w_src[b,l,:]·fck_w[q,:] + fck_b[q] ----
__global__ void k_keys(const float* __restrict__ wsrc, const float* __restrict__ fckw,
                       const float* __restrict__ fckb, float* __restrict__ kmat) {
  int b = blockIdx.x / Ln, l = blockIdx.x % Ln;
  __shared__ float row[Dn];
  row[threadIdx.x] = wsrc[(b * Ln + l) * Dn + threadIdx.x];
  __syncthreads();
  int q = threadIdx.x;
  const float* wq = fckw + q * Dn;
  float acc = fckb[q];
#pragma unroll 8
  for (int d = 0; d < Dn; ++d) acc += row[d] * wq[d];
  kmat[(b * Ln + l) * Qn + q] = acc;
}

// ---------------- kernel 2: scores/argmax/w_alloc/bias0 ----------------------
__global__ void k_alloc(const float* __restrict__ wsrc, const float* __restrict__ wtgt,
                        const float* __restrict__ conv0b, const float* __restrict__ kmat,
                        float* __restrict__ walloc, float* __restrict__ bias0) {
  int b = blockIdx.x;
  __shared__ float S[Ln][Dn];
  __shared__ float T[Ln][Dn];
  __shared__ double sc[Ln][Ln];
  __shared__ double cs[Ln];
  __shared__ int idx[Ln];
  int tid = threadIdx.x;
  for (int n = tid; n < Ln * Dn; n += 256) {
    S[n >> 8][n & 255] = wsrc[b * Ln * Dn + n];
    T[n >> 8][n & 255] = wtgt[b * Ln * Dn + n];
  }
  __syncthreads();
  for (int p = tid; p < Ln * Ln; p += 256) {
    int l = p / Ln, m = p % Ln;
    double a = 0.0;
    for (int d = 0; d < Dn; ++d) a += (double)S[l][d] * (double)T[m][d];
    sc[l][m] = a;
  }
  __syncthreads();
  if (tid < Ln) {
    double a = 0.0;
    for (int l = 0; l < Ln; ++l) a += sc[l][tid];
    cs[tid] = a;
  }
  __syncthreads();
  if (tid < Ln) {
    double best = -1e300; int bi = 0;
    for (int m = 0; m < Ln; ++m) {
      double v = cs[m] - sc[tid][m];
      if (v > best) { best = v; bi = m; }
    }
    idx[tid] = bi;
  }
  __syncthreads();
  for (int n = tid; n < Ln * Dn; n += 256) {
    int l = n >> 8, d = n & 255;
    walloc[b * Ln * Dn + n] = T[idx[l]][d];
  }
  if (tid < Ln) {
    float a = 0.f;
    const float* kr = kmat + (b * Ln + tid) * Qn;
    for (int q = 0; q < Qn; ++q) a += conv0b[q] * kr[q];
    bias0[b * Ln + tid] = a;
  }
}

// ---------------- kernel 3: M[b,l,c] and bg[b,l,e] ---------------------------
__global__ void k_mbg(const float* __restrict__ kmat, const float* __restrict__ conv0w,
                      const float* __restrict__ walloc, const float* __restrict__ fcw,
                      const float* __restrict__ fcb,
                      float* __restrict__ Mmat, float* __restrict__ bg) {
  int bid = blockIdx.x;
  __shared__ float row[Dn];
  if (bid < Bn * Ln) {
    int b = bid / Ln, l = bid % Ln;
    row[threadIdx.x] = kmat[(b * Ln + l) * Qn + threadIdx.x];
    __syncthreads();
    int c = threadIdx.x;
    float acc = 0.f;
    for (int q = 0; q < Qn; ++q) acc += row[q] * conv0w[q * Cn + c];
    Mmat[(b * Ln + l) * Cn + c] = acc;
  } else {
    int id = bid - Bn * Ln;
    int b = id / Ln, l = id % Ln;
    row[threadIdx.x] = walloc[(b * Ln + l) * Dn + threadIdx.x];
    __syncthreads();
    for (int it = 0; it < 2; ++it) {
      int e = it * 256 + threadIdx.x;
      const float* we = fcw + e * Dn;
      float acc = fcb[e];
      for (int d = 0; d < Dn; ++d) acc += row[d] * we[d];
      bg[(b * Ln + l) * (2 * Cn) + e] = acc;
    }
  }
}

// ---------------- kernel 4: G (plain row-major [b][g][m=128][k=256]) + bv ----
// rows m: 0..63 gamma (c_out = g*64+m, bg col 256+c_out); 64..127 beta (bg col c_out)
__global__ void k_gbuild(const float* __restrict__ Mmat, const float* __restrict__ bg,
                         const float* __restrict__ bias0,
                         unsigned short* __restrict__ Gt, float* __restrict__ bv) {
  int g = blockIdx.x, b = blockIdx.y;
  __shared__ float Ms[Ln][Dn];
  __shared__ float Gb[Ln][128];
  __shared__ float B0[Ln];
  int tid = threadIdx.x;
  for (int n = tid; n < Ln * Dn; n += 256) Ms[n >> 8][n & 255] = Mmat[b * Ln * Dn + n];
  for (int n = tid; n < Ln * 128; n += 256) {
    int l = n >> 7, j = n & 127;
    int e = (j < 64) ? (Cn + g * 64 + j) : (g * 64 + (j - 64));
    Gb[l][j] = bg[(b * Ln + l) * (2 * Cn) + e];
  }
  if (tid < Ln) B0[tid] = bias0[b * Ln + tid];
  __syncthreads();
  unsigned long base = (unsigned long)(b * 4 + g) * (128 * 256);
  for (int m = 0; m < 128; ++m) {
    float acc = 0.f;
#pragma unroll
    for (int l = 0; l < Ln; ++l) acc += Ms[l][tid] * Gb[l][m];
    Gt[base + (unsigned long)m * 256 + tid] = f2bf(acc);
  }
  if (tid < 128) {
    float a = 0.f;
#pragma unroll
    for (int l = 0; l < Ln; ++l) a += B0[l] * Gb[l][tid];
    bv[b * 512 + g * 128 + tid] = a;
  }
}

// ---------------- kernel 5: instance-norm partials + h -> h_T (bf16) --------
// phase 1: f32 load + bf16 cvt + LDS transpose tile.  phase 2: transposed
// reads accumulate per-thread (s,s2) (no shuffle chains) + write hT.
__global__ void k_stats_tr(const float* __restrict__ h, unsigned short* __restrict__ hT,
                           float* __restrict__ part) {
  int hwc = blockIdx.x;  // 64 chunks of 256 hw
  int cc  = blockIdx.y;  // 4 chunks of 64 c
  int b   = blockIdx.z;
  int tid = threadIdx.x;
  int w = tid >> 6, lane = tid & 63;
  __shared__ unsigned short tile[64 * 258];
  __shared__ float red[64 * 17 + 16];
  const int c0 = cc * 64, hw0 = hwc * 256;
  for (int i = 0; i < 16; ++i) {
    int cl = i * 4 + w;
    f32x4 v = *(const f32x4*)(h + ((unsigned long)(b * Cn + c0 + cl)) * HW + hw0 + lane * 4);
    unsigned lo = (unsigned)f2bf(v.x) | ((unsigned)f2bf(v.y) << 16);
    unsigned hi = (unsigned)f2bf(v.z) | ((unsigned)f2bf(v.w) << 16);
    unsigned* dst = (unsigned*)(tile + cl * 258 + lane * 4);
    dst[0] = lo; dst[1] = hi;
  }
  __syncthreads();
  int cp = tid & 31, sub = tid >> 5;
  float s0 = 0.f, s20 = 0.f, s1 = 0.f, s21 = 0.f;
  for (int i = 0; i < 32; ++i) {
    int hw = i * 8 + sub;
    unsigned short a0 = tile[(2 * cp) * 258 + hw];
    unsigned short a1 = tile[(2 * cp + 1) * 258 + hw];
    float f0 = bf2f(a0), f1 = bf2f(a1);
    s0 += f0; s20 += f0 * f0; s1 += f1; s21 += f1 * f1;
    unsigned pk = (unsigned)a0 | ((unsigned)a1 << 16);
    *(unsigned*)(hT + ((unsigned long)b * HW + hw0 + hw) * Cn + c0 + 2 * cp) = pk;
  }
  red[(2 * cp) * 17 + sub * 2]     = s0;
  red[(2 * cp) * 17 + sub * 2 + 1] = s20;
  red[(2 * cp + 1) * 17 + sub * 2]     = s1;
  red[(2 * cp + 1) * 17 + sub * 2 + 1] = s21;
  __syncthreads();
  if (tid < 64) {
    float a = 0.f, q = 0.f;
#pragma unroll
    for (int j = 0; j < 8; ++j) { a += red[tid * 17 + j * 2]; q += red[tid * 17 + j * 2 + 1]; }
    float* pp = part + (((unsigned long)(b * Cn + c0 + tid)) * 64 + hwc) * 2;
    pp[0] = a; pp[1] = q;
  }
}

// ---------------- kernel 6: finalize stats -> scale/shift --------------------
__global__ void k_fin(const float* __restrict__ part, const float* __restrict__ inw,
                      const float* __restrict__ inb, float* __restrict__ ss) {
  int id = blockIdx.x * 256 + threadIdx.x;  // 4096 = B*C
  int c = id & 255;
  float s = 0.f, s2 = 0.f;
  const float* pp = part + (unsigned long)id * 128;
  for (int j = 0; j < 64; ++j) { s += pp[2 * j]; s2 += pp[2 * j + 1]; }
  float mean = s * (1.0f / HW);
  float var = s2 * (1.0f / HW) - mean * mean;
  float rs = rsqrtf(var + 1e-5f);
  float scv = rs * inw[c];
  float sh = inb[c] - mean * scv;
  ss[id * 2] = scv; ss[id * 2 + 1] = sh;
}

// ---------------- kernel 7: main fused GEMM + epilogue -----------------------
// A,B MFMA fragments loaded DIRECTLY from global (no LDS staging, no K-loop
// barriers). LDS holds only the 16 KB swizzled h-tile for the epilogue.
__global__ __launch_bounds__(256, 2) void k_main(
    const unsigned short* __restrict__ hT, const unsigned short* __restrict__ Gt,
    const float* __restrict__ bv, const float* __restrict__ ss,
    float* __restrict__ out) {
  int b = blockIdx.y;
  unsigned x = blockIdx.x;                // 512 = 8 XCD chunks x 64
  unsigned wg = (x & 7) * 64 + (x >> 3);  // bijective XCD swizzle
  int g = wg & 3, hwt = wg >> 2;
  int hw0 = hwt * 128;
  int tid = threadIdx.x;
  int w = tid >> 6, lane = tid & 63;
  int wr = w >> 1, wc = w & 1;
  int lr = lane & 15, lg = lane >> 4;

  __shared__ __align__(16) unsigned char Eb[16384];

  const unsigned short* Gblob = Gt + (unsigned long)(b * 4 + g) * (128 * 256);
  const unsigned short* hTb = hT + (unsigned long)b * HW * Cn;

  // stage epilogue tile: hT[hw0..hw0+127][g*64..+64) -> swizzled LDS image
  // (linear dest, inverse-swizzled global source: rule 21)
#pragma unroll
  for (int j = 0; j < 4; ++j) {
    int seg = j * 4 + w;
    unsigned a = seg * 1024 + lane * 16;
    int hwR = a >> 7, blk = (a >> 4) & 7;
    const void* src = (const char*)(hTb + (unsigned long)(hw0 + hwR) * Cn + g * 64) +
                      ((blk ^ (hwR & 7)) * 16);
    gl_lds16(src, &Eb[seg * 1024]);
  }

  f32x4 acc[4][4];
#pragma unroll
  for (int i = 0; i < 4; ++i)
#pragma unroll
    for (int j = 0; j < 4; ++j) acc[i][j] = (f32x4){0.f, 0.f, 0.f, 0.f};

  // fragment base pointers (k part: lg*8; per-kk advance folds into imm offset)
  const unsigned short* pA[4];
  const unsigned short* pB[4];
#pragma unroll
  for (int jm = 0; jm < 4; ++jm) {
    int rowA = (jm >> 1) * 64 + wr * 32 + (jm & 1) * 16 + lr;
    pA[jm] = Gblob + rowA * 256 + lg * 8;
  }
#pragma unroll
  for (int jn = 0; jn < 4; ++jn) {
    pB[jn] = hTb + (unsigned long)(hw0 + wc * 64 + jn * 16 + lr) * Cn + lg * 8;
  }

#pragma unroll
  for (int kk = 0; kk < 8; ++kk) {
    short8 afr[4], bfr[4];
#pragma unroll
    for (int jm = 0; jm < 4; ++jm) afr[jm] = *(const short8*)(pA[jm] + kk * 32);
#pragma unroll
    for (int jn = 0; jn < 4; ++jn) bfr[jn] = *(const short8*)(pB[jn] + kk * 32);
#pragma unroll
    for (int jm = 0; jm < 4; ++jm)
#pragma unroll
      for (int jn = 0; jn < 4; ++jn)
        acc[jm][jn] = __builtin_amdgcn_mfma_f32_16x16x32_bf16(afr[jm], bfr[jn], acc[jm][jn], 0, 0, 0);
  }

  __syncthreads();  // drains the epilogue-tile DMA (only barrier in kernel)

  const float* ssb = ss + (b * Cn) * 2;
  const float* bvb = bv + b * 512 + g * 128;
#pragma unroll
  for (int p = 0; p < 2; ++p) {
#pragma unroll
    for (int r = 0; r < 4; ++r) {
      int mloc = wr * 32 + p * 16 + lg * 4 + r;  // 0..63
      int cg = g * 64 + mloc;
      float scv = ssb[cg * 2], sh = ssb[cg * 2 + 1];
      float bvg = bvb[mloc];
      float bvbeta = bvb[64 + mloc];
#pragma unroll
      for (int jn = 0; jn < 4; ++jn) {
        int row = wc * 64 + jn * 16 + lr;  // hw within tile
        unsigned off = (unsigned)((row * 128 + mloc * 2) ^ ((row & 7) << 4));
        float hv = bf2f(*(const unsigned short*)(&Eb[0] + off));
        float hn = hv * scv + sh;
        float gm = acc[p][jn][r] + bvg;
        float bt = acc[2 + p][jn][r] + bvbeta;
        int hwg = hw0 + wc * 64 + jn * 16 + lr;
        out[((unsigned long)(b * Cn + cg)) * HW + hwg] = hn * gm + bt;
      }
    }
  }
}

__global__ void k_sentinel(float* out) { out[0] = 12345.0f; }

// ---------------- launcher ---------------------------------------------------
extern "C" void kernel_launch(void* const* d_in, const int* in_sizes, int n_in,
                              void* d_out, int out_size, void* d_ws, size_t ws_size,
                              hipStream_t stream) {
  const float* wsrc   = (const float*)d_in[0];
  const float* wtgt   = (const float*)d_in[1];
  const float* h      = (const float*)d_in[2];
  const float* conv0w = (const float*)d_in[3];
  const float* conv0b = (const float*)d_in[4];
  const float* fckw   = (const float*)d_in[5];
  const float* fckb   = (const float*)d_in[6];
  const float* fcw    = (const float*)d_in[7];
  const float* fcb    = (const float*)d_in[8];
  const float* inw    = (const float*)d_in[9];
  const float* inb    = (const float*)d_in[10];
  float* out = (float*)d_out;
  char* ws = (char*)d_ws;

  const size_t NEED = 142542848ull;
  if (ws_size < NEED) {
    k_sentinel<<<1, 1, 0, stream>>>(out);
    return;
  }

  unsigned short* hT = (unsigned short*)(ws + 0);           // 134217728
  float* kmat   = (float*)(ws + 134217728);                 // 393216
  float* walloc = (float*)(ws + 134610944);                 // 393216
  float* bias0  = (float*)(ws + 135004160);                 // 2048
  float* bg     = (float*)(ws + 135006208);                 // 786432
  float* Mmat   = (float*)(ws + 135792640);                 // 393216
  unsigned short* Gt = (unsigned short*)(ws + 136185856);   // 4194304
  float* bv     = (float*)(ws + 140380160);                 // 32768
  float* part   = (float*)(ws + 140412928);                 // 2097152
  float* ss     = (float*)(ws + 142510080);                 // 32768

  dim3 gs(64, 4, Bn);
  k_stats_tr<<<gs, 256, 0, stream>>>(h, hT, part);
  k_keys<<<Bn * Ln, 256, 0, stream>>>(wsrc, fckw, fckb, kmat);
  k_alloc<<<Bn, 256, 0, stream>>>(wsrc, wtgt, conv0b, kmat, walloc, bias0);
  k_mbg<<<2 * Bn * Ln, 256, 0, stream>>>(kmat, conv0w, walloc, fcw, fcb, Mmat, bg);
  dim3 gg(4, Bn);
  k_gbuild<<<gg, 256, 0, stream>>>(Mmat, bg, bias0, Gt, bv);
  k_fin<<<16, 256, 0, stream>>>(part, inw, inb, ss);
  dim3 gm(512, Bn);
  k_main<<<gm, 256, 0, stream>>>(hT, Gt, bv, ss, out);
}

// Round 3
// 354.979 us; speedup vs baseline: 1.2917x; 1.2917x over previous
//
#include <hip/hip_runtime.h>
#include <stdint.h>

#define HW 16384
#define Bn 16
#define Ln 24
#define Dn 256
#define Qn 256
#define Cn 256

typedef __attribute__((ext_vector_type(8))) short short8;
typedef __attribute__((ext_vector_type(4))) float f32x4;
typedef __attribute__((ext_vector_type(4))) unsigned short u16x4;

__device__ __forceinline__ unsigned short f2bf(float f) {
  unsigned u = __builtin_bit_cast(unsigned, f);
  u += 0x7FFFu + ((u >> 16) & 1u);
  return (unsigned short)(u >> 16);
}
__device__ __forceinline__ float bf2f(unsigned short s) {
  return __builtin_bit_cast(float, (unsigned)s << 16);
}

__device__ __forceinline__ void gl_lds16(const void* gsrc, void* lds) {
  __builtin_amdgcn_global_load_lds(
      (const __attribute__((address_space(1))) unsigned int*)gsrc,
      (__attribute__((address_space(3))) unsigned int*)lds, 16, 0, 0);
}

// ---------------- kernel 1: k[b,l,q] = w_src[b,l,:]·fck_w[q,:] + fck_b[q] ----
__global__ void k_keys(const float* __restrict__ wsrc, const float* __restrict__ fckw,
                       const float* __restrict__ fckb, float* __restrict__ kmat) {
  int b = blockIdx.x / Ln, l = blockIdx.x % Ln;
  __shared__ float row[Dn];
  row[threadIdx.x] = wsrc[(b * Ln + l) * Dn + threadIdx.x];
  __syncthreads();
  int q = threadIdx.x;
  const float* wq = fckw + q * Dn;
  float acc = fckb[q];
#pragma unroll 8
  for (int d = 0; d < Dn; ++d) acc += row[d] * wq[d];
  kmat[(b * Ln + l) * Qn + q] = acc;
}

// ---------------- kernel 2: scores/argmax/w_alloc/bias0 ----------------------
__global__ void k_alloc(const float* __restrict__ wsrc, const float* __restrict__ wtgt,
                        const float* __restrict__ conv0b, const float* __restrict__ kmat,
                        float* __restrict__ walloc, float* __restrict__ bias0) {
  int b = blockIdx.x;
  __shared__ float S[Ln][Dn];
  __shared__ float T[Ln][Dn];
  __shared__ double sc[Ln][Ln];
  __shared__ double cs[Ln];
  __shared__ int idx[Ln];
  int tid = threadIdx.x;
  for (int n = tid; n < Ln * Dn; n += 256) {
    S[n >> 8][n & 255] = wsrc[b * Ln * Dn + n];
    T[n >> 8][n & 255] = wtgt[b * Ln * Dn + n];
  }
  __syncthreads();
  for (int p = tid; p < Ln * Ln; p += 256) {
    int l = p / Ln, m = p % Ln;
    double a = 0.0;
    for (int d = 0; d < Dn; ++d) a += (double)S[l][d] * (double)T[m][d];
    sc[l][m] = a;
  }
  __syncthreads();
  if (tid < Ln) {
    double a = 0.0;
    for (int l = 0; l < Ln; ++l) a += sc[l][tid];
    cs[tid] = a;
  }
  __syncthreads();
  if (tid < Ln) {
    double best = -1e300; int bi = 0;
    for (int m = 0; m < Ln; ++m) {
      double v = cs[m] - sc[tid][m];
      if (v > best) { best = v; bi = m; }
    }
    idx[tid] = bi;
  }
  __syncthreads();
  for (int n = tid; n < Ln * Dn; n += 256) {
    int l = n >> 8, d = n & 255;
    walloc[b * Ln * Dn + n] = T[idx[l]][d];
  }
  if (tid < Ln) {
    float a = 0.f;
    const float* kr = kmat + (b * Ln + tid) * Qn;
    for (int q = 0; q < Qn; ++q) a += conv0b[q] * kr[q];
    bias0[b * Ln + tid] = a;
  }
}

// ---------------- kernel 3: M[b,l,c] and bg[b,l,e] ---------------------------
__global__ void k_mbg(const float* __restrict__ kmat, const float* __restrict__ conv0w,
                      const float* __restrict__ walloc, const float* __restrict__ fcw,
                      const float* __restrict__ fcb,
                      float* __restrict__ Mmat, float* __restrict__ bg) {
  int bid = blockIdx.x;
  __shared__ float row[Dn];
  if (bid < Bn * Ln) {
    int b = bid / Ln, l = bid % Ln;
    row[threadIdx.x] = kmat[(b * Ln + l) * Qn + threadIdx.x];
    __syncthreads();
    int c = threadIdx.x;
    float acc = 0.f;
    for (int q = 0; q < Qn; ++q) acc += row[q] * conv0w[q * Cn + c];
    Mmat[(b * Ln + l) * Cn + c] = acc;
  } else {
    int id = bid - Bn * Ln;
    int b = id / Ln, l = id % Ln;
    row[threadIdx.x] = walloc[(b * Ln + l) * Dn + threadIdx.x];
    __syncthreads();
    for (int it = 0; it < 2; ++it) {
      int e = it * 256 + threadIdx.x;
      const float* we = fcw + e * Dn;
      float acc = fcb[e];
      for (int d = 0; d < Dn; ++d) acc += row[d] * we[d];
      bg[(b * Ln + l) * (2 * Cn) + e] = acc;
    }
  }
}

// ---------------- kernel 4: G blob per (b,g): pre-swizzled LDS image + bv ----
// 128 rows x 256 k bf16, 64KB. Row r: wave = r>>5, beta = (r>>4)&1,
// c_loc = (r>>5)*16 + (r&15)  (so gamma/beta of a channel are m-frag0/1 of
// the SAME wave). byte = (r*512 + k*2) ^ ((r&7)<<4).
__global__ void k_gbuild(const float* __restrict__ Mmat, const float* __restrict__ bg,
                         const float* __restrict__ bias0,
                         unsigned short* __restrict__ Gt, float* __restrict__ bv) {
  int g = blockIdx.x, b = blockIdx.y;
  __shared__ float Ms[Ln][Dn];
  __shared__ float Gb[Ln][128];
  __shared__ float B0[Ln];
  int tid = threadIdx.x;
  for (int n = tid; n < Ln * Dn; n += 256) Ms[n >> 8][n & 255] = Mmat[b * Ln * Dn + n];
  for (int n = tid; n < Ln * 128; n += 256) {
    int l = n >> 7, j = n & 127;
    int e = (j < 64) ? (Cn + g * 64 + j) : (g * 64 + (j - 64));
    Gb[l][j] = bg[(b * Ln + l) * (2 * Cn) + e];
  }
  if (tid < Ln) B0[tid] = bias0[b * Ln + tid];
  __syncthreads();
  char* base = (char*)Gt + (unsigned long)(b * 4 + g) * 65536;
  for (int r = 0; r < 128; ++r) {
    int isb = (r >> 4) & 1;
    int c_loc = (r >> 5) * 16 + (r & 15);
    int j = c_loc + isb * 64;
    float acc = 0.f;
#pragma unroll
    for (int l = 0; l < Ln; ++l) acc += Ms[l][tid] * Gb[l][j];
    unsigned off = (unsigned)((r * 512 + tid * 2) ^ ((r & 7) << 4));
    *(unsigned short*)(base + off) = f2bf(acc);
  }
  if (tid < 128) {
    float a = 0.f;
#pragma unroll
    for (int l = 0; l < Ln; ++l) a += B0[l] * Gb[l][tid];
    bv[b * 512 + g * 128 + tid] = a;  // 0..63 gamma-bias, 64..127 beta-bias
  }
}

// ---------------- kernel 5: stats (one (b,c) row per block) -> scale/shift ---
__global__ void k_stats(const float* __restrict__ h, const float* __restrict__ inw,
                        const float* __restrict__ inb, float* __restrict__ ss) {
  int id = blockIdx.x;  // b*256 + c
  const float* row = h + (unsigned long)id * HW;
  int tid = threadIdx.x;
  float s = 0.f, s2 = 0.f;
#pragma unroll
  for (int i = 0; i < 16; ++i) {
    f32x4 v = *(const f32x4*)(row + i * 1024 + tid * 4);
    s += v.x + v.y + v.z + v.w;
    s2 += v.x * v.x + v.y * v.y + v.z * v.z + v.w * v.w;
  }
#pragma unroll
  for (int o = 1; o < 64; o <<= 1) { s += __shfl_xor(s, o); s2 += __shfl_xor(s2, o); }
  __shared__ float red[8];
  int w = tid >> 6;
  if ((tid & 63) == 0) { red[w * 2] = s; red[w * 2 + 1] = s2; }
  __syncthreads();
  if (tid == 0) {
    float a = red[0] + red[2] + red[4] + red[6];
    float q = red[1] + red[3] + red[5] + red[7];
    float mean = a * (1.0f / HW);
    float var = q * (1.0f / HW) - mean * mean;
    float rs = rsqrtf(var + 1e-5f);
    int c = id & 255;
    float scv = rs * inw[c];
    ss[id * 2] = scv;
    ss[id * 2 + 1] = inb[c] - mean * scv;
  }
}

// ---------------- kernel 6: main fused GEMM + epilogue -----------------------
__device__ __forceinline__ void xpose_write(unsigned char* buf, const f32x4* R,
                                            int hwq, int cg) {
#pragma unroll
  for (int e = 0; e < 4; ++e) {
    int hwl = hwq * 4 + e;
    u16x4 pk;
    pk[0] = f2bf(R[0][e]); pk[1] = f2bf(R[1][e]);
    pk[2] = f2bf(R[2][e]); pk[3] = f2bf(R[3][e]);
    *(u16x4*)(buf + ((hwl * 64 + cg * 8) ^ (((hwl >> 1) & 3) << 4))) = pk;
  }
}

__global__ __launch_bounds__(256, 2) void k_main(
    const float* __restrict__ h, const unsigned short* __restrict__ Gt,
    const float* __restrict__ bv, const float* __restrict__ ss,
    float* __restrict__ out) {
  int b = blockIdx.y;
  unsigned x = blockIdx.x;                // 512 = 8 XCD chunks x 64
  unsigned wg = (x & 7) * 64 + (x >> 3);  // bijective XCD swizzle
  int g = wg & 3, hwt = wg >> 2;
  int hw0 = hwt * 128;
  int tid = threadIdx.x;
  int w = tid >> 6, lane = tid & 63;
  int lr = lane & 15, lg = lane >> 4;

  __shared__ __align__(16) unsigned char Ab[65536];
  __shared__ __align__(16) unsigned char Bb[2][8192];

  const float* hb = h + (unsigned long)(b * Cn) * HW;

  // A: DMA the pre-swizzled 64KB G blob, linear (issued first; in-order
  // vmcnt retire means it's complete before any later f32 load is consumed).
  const char* Gblob = (const char*)Gt + (unsigned long)(b * 4 + g) * 65536;
#pragma unroll
  for (int i = 0; i < 16; ++i)
    gl_lds16(Gblob + i * 4096 + w * 1024 + (lane * 16), &Ab[i * 4096 + w * 1024]);

  // chunk order: the two k-chunks holding this block's output channels go
  // LAST so they remain in the double-buffer for the epilogue h-snapshot.
  int skip = 2 * g;
  int ord[8];
#pragma unroll
  for (int j = 0; j < 6; ++j) ord[j] = j + (j >= skip ? 2 : 0);
  ord[6] = skip; ord[7] = skip + 1;

  int hwq = tid & 31, cg = tid >> 5;  // per-thread transpose coords
  const float* hcol = hb + hw0 + hwq * 4;

  f32x4 Ra[4], Rb[4];
#pragma unroll
  for (int gi = 0; gi < 4; ++gi)
    Ra[gi] = *(const f32x4*)(hcol + (unsigned long)(ord[0] * 32 + cg * 4 + gi) * HW);
#pragma unroll
  for (int gi = 0; gi < 4; ++gi)
    Rb[gi] = *(const f32x4*)(hcol + (unsigned long)(ord[1] * 32 + cg * 4 + gi) * HW);
  xpose_write(&Bb[0][0], Ra, hwq, cg);

  f32x4 acc[2][8];
#pragma unroll
  for (int mf = 0; mf < 2; ++mf)
#pragma unroll
    for (int nf = 0; nf < 8; ++nf) acc[mf][nf] = (f32x4){0.f, 0.f, 0.f, 0.f};

  int rowb0 = (w * 32 + lr) * 512;
  int rowb1 = (w * 32 + 16 + lr) * 512;
  int aswz = (lr & 7) << 4;

#pragma unroll
  for (int j = 0; j < 8; ++j) {
    // make this iter's LDS writes visible, then sync — NO vmcnt drain.
    asm volatile("s_waitcnt lgkmcnt(0)" ::: "memory");
    __builtin_amdgcn_sched_barrier(0);
    __builtin_amdgcn_s_barrier();
    __builtin_amdgcn_sched_barrier(0);

    if (j < 6) {  // prefetch f32 for chunk ord[j+2]
      f32x4* R = (j & 1) ? Rb : Ra;
#pragma unroll
      for (int gi = 0; gi < 4; ++gi)
        R[gi] = *(const f32x4*)(hcol + (unsigned long)(ord[j + 2] * 32 + cg * 4 + gi) * HW);
    }
    if (j < 7) {  // transpose-write chunk ord[j+1] into the other buffer
      const f32x4* R = (j & 1) ? Ra : Rb;
      xpose_write(&Bb[(j + 1) & 1][0], R, hwq, cg);
    }

    // compute chunk ord[j] from Bb[j&1]
    int kb = ord[j] * 64 + lg * 16;
    short8 a0 = *(const short8*)(&Ab[rowb0 + (kb ^ aswz)]);
    short8 a1 = *(const short8*)(&Ab[rowb1 + (kb ^ aswz)]);
    const unsigned char* bbuf = &Bb[j & 1][0];
#pragma unroll
    for (int nf = 0; nf < 8; ++nf) {
      int hwl = nf * 16 + lr;
      short8 bf = *(const short8*)(&bbuf[(hwl * 64 + lg * 16) ^ (((hwl >> 1) & 3) << 4)]);
      acc[0][nf] = __builtin_amdgcn_mfma_f32_16x16x32_bf16(a0, bf, acc[0][nf], 0, 0, 0);
      acc[1][nf] = __builtin_amdgcn_mfma_f32_16x16x32_bf16(a1, bf, acc[1][nf], 0, 0, 0);
    }
  }

  // epilogue: out = (h*sc+sh)*(accG+bvG) + (accB+bvB); h bf16 comes from the
  // two resident B-chunks (processed last, halves in Bb[0] / Bb[1]).
  const float* ssb = ss + b * Cn * 2;
  const float* bvb = bv + b * 512 + g * 128;
  const unsigned char* ebuf = &Bb[w >> 1][0];
  int kloc = (w & 1) * 16 + lg * 4;
#pragma unroll
  for (int r = 0; r < 4; ++r) {
    int c_loc = w * 16 + lg * 4 + r;  // 0..63
    int c = g * 64 + c_loc;
    float scv = ssb[c * 2], sh = ssb[c * 2 + 1];
    float bvg = bvb[c_loc], bvbt = bvb[64 + c_loc];
    float* orow = out + (unsigned long)(b * Cn + c) * HW + hw0;
#pragma unroll
    for (int nf = 0; nf < 8; ++nf) {
      int hwl = nf * 16 + lr;
      unsigned short hbits = *(const unsigned short*)(
          &ebuf[(hwl * 64 + (kloc + r) * 2) ^ (((hwl >> 1) & 3) << 4)]);
      float hn = bf2f(hbits) * scv + sh;
      orow[hwl] = hn * (acc[0][nf][r] + bvg) + (acc[1][nf][r] + bvbt);
    }
  }
}

__global__ void k_sentinel(float* out) { out[0] = 12345.0f; }

// ---------------- launcher ---------------------------------------------------
extern "C" void kernel_launch(void* const* d_in, const int* in_sizes, int n_in,
                              void* d_out, int out_size, void* d_ws, size_t ws_size,
                              hipStream_t stream) {
  const float* wsrc   = (const float*)d_in[0];
  const float* wtgt   = (const float*)d_in[1];
  const float* h      = (const float*)d_in[2];
  const float* conv0w = (const float*)d_in[3];
  const float* conv0b = (const float*)d_in[4];
  const float* fckw   = (const float*)d_in[5];
  const float* fckb   = (const float*)d_in[6];
  const float* fcw    = (const float*)d_in[7];
  const float* fcb    = (const float*)d_in[8];
  const float* inw    = (const float*)d_in[9];
  const float* inb    = (const float*)d_in[10];
  float* out = (float*)d_out;
  char* ws = (char*)d_ws;

  const size_t NEED = 6227968ull;
  if (ws_size < NEED) {
    k_sentinel<<<1, 1, 0, stream>>>(out);
    return;
  }

  float* kmat   = (float*)(ws + 0);                 // 393216
  float* walloc = (float*)(ws + 393216);            // 393216
  float* bias0  = (float*)(ws + 786432);            // 2048
  float* bg     = (float*)(ws + 788480);            // 786432
  float* Mmat   = (float*)(ws + 1574912);           // 393216
  unsigned short* Gt = (unsigned short*)(ws + 1968128);  // 4194304
  float* bv     = (float*)(ws + 6162432);           // 32768
  float* ss     = (float*)(ws + 6195200);           // 32768

  k_keys<<<Bn * Ln, 256, 0, stream>>>(wsrc, fckw, fckb, kmat);
  k_alloc<<<Bn, 256, 0, stream>>>(wsrc, wtgt, conv0b, kmat, walloc, bias0);
  k_mbg<<<2 * Bn * Ln, 256, 0, stream>>>(kmat, conv0w, walloc, fcw, fcb, Mmat, bg);
  dim3 gg(4, Bn);
  k_gbuild<<<gg, 256, 0, stream>>>(Mmat, bg, bias0, Gt, bv);
  k_stats<<<Bn * Cn, 256, 0, stream>>>(h, inw, inb, ss);
  dim3 gm(512, Bn);
  k_main<<<gm, 256, 0, stream>>>(h, Gt, bv, ss, out);
}